// Round 1
// baseline (271.007 us; speedup 1.0000x reference)
//
#include <hip/hip_runtime.h>

namespace {

constexpr int GV   = 48;
constexpr int NV   = 8;
constexpr int NH   = 27;
constexpr int NW   = 27;
constexpr int L    = NH * NW;     // 729
constexpr int C    = 1152;
constexpr int CD   = 288;
constexpr int NPTS = NV * L;      // 5832
constexpr int NVOX = GV * GV * GV;// 110592

__global__ __launch_bounds__(256) void k_zero_cnt(float* __restrict__ cnt) {
    int i = blockIdx.x * 256 + threadIdx.x;
    if (i < NVOX) cnt[i] = 0.f;
}

// Zero only the voxel cells that will be scattered into (sums grid is otherwise
// never read: conv gather guards on cnt>0).
__global__ __launch_bounds__(CD) void k_zero_touched(const int* __restrict__ coords,
                                                     float* __restrict__ sums) {
    int p = blockIdx.x;
    int c0 = coords[p * 3 + 0], c1 = coords[p * 3 + 1], c2 = coords[p * 3 + 2];
    int flat = (c0 * GV + c1) * GV + c2;
    sums[(size_t)flat * CD + threadIdx.x] = 0.f;
}

__global__ __launch_bounds__(CD) void k_scatter(const int* __restrict__ coords,
                                                const float* __restrict__ x,
                                                float* __restrict__ sums,
                                                float* __restrict__ cnt) {
    int p = blockIdx.x;
    int t = threadIdx.x;
    int c0 = coords[p * 3 + 0], c1 = coords[p * 3 + 1], c2 = coords[p * 3 + 2];
    int flat = (c0 * GV + c1) * GV + c2;
    atomicAdd(&sums[(size_t)flat * CD + t], x[(size_t)p * CD + t]);
    if (t == 0) atomicAdd(&cnt[flat], 1.0f);
}

__device__ __forceinline__ float gelu_tanh(float a) {
    float a3 = a * a * a;
    float inner = 0.7978845608028654f * (a + 0.044715f * a3);
    return 0.5f * a * (1.0f + tanhf(inner));
}

// Depthwise 3x3x3 conv evaluated ONLY at gathered voxels, + gelu.
__global__ __launch_bounds__(CD) void k_conv3_gather(const int* __restrict__ coords,
                                                     const float* __restrict__ sums,
                                                     const float* __restrict__ cnt,
                                                     const float* __restrict__ w3,
                                                     float* __restrict__ ptf) {
    int p = blockIdx.x;
    int t = threadIdx.x;
    int c0 = coords[p * 3 + 0], c1 = coords[p * 3 + 1], c2 = coords[p * 3 + 2];
    float acc = 0.f;
#pragma unroll
    for (int dz = 0; dz < 3; ++dz) {
        int z = c0 + dz - 1;
        if ((unsigned)z >= (unsigned)GV) continue;
#pragma unroll
        for (int dy = 0; dy < 3; ++dy) {
            int y = c1 + dy - 1;
            if ((unsigned)y >= (unsigned)GV) continue;
#pragma unroll
            for (int dx = 0; dx < 3; ++dx) {
                int x2 = c2 + dx - 1;
                if ((unsigned)x2 >= (unsigned)GV) continue;
                int n = (z * GV + y) * GV + x2;
                float cv = cnt[n];             // broadcast across block
                if (cv > 0.f) {
                    float w = w3[t * 27 + dz * 9 + dy * 3 + dx];
                    acc += w * (sums[(size_t)n * CD + t] / cv);
                }
            }
        }
    }
    ptf[(size_t)p * CD + t] = gelu_tanh(acc);
}

// Depthwise 3x3 conv2d over (V,27,27,CD) channel-last.
__global__ __launch_bounds__(CD) void k_conv2(const float* __restrict__ ptf,
                                              const float* __restrict__ w2,
                                              float* __restrict__ sm) {
    int p = blockIdx.x;
    int t = threadIdx.x;
    int v = p / L;
    int rem = p - v * L;
    int y = rem / NW;
    int x = rem - y * NW;
    float acc = 0.f;
#pragma unroll
    for (int dy = 0; dy < 3; ++dy) {
        int yy = y + dy - 1;
        if ((unsigned)yy >= (unsigned)NH) continue;
#pragma unroll
        for (int dx = 0; dx < 3; ++dx) {
            int xx = x + dx - 1;
            if ((unsigned)xx >= (unsigned)NW) continue;
            acc += w2[t * 9 + dy * 3 + dx] *
                   ptf[((size_t)v * L + yy * NW + xx) * CD + t];
        }
    }
    sm[(size_t)p * CD + t] = acc;
}

// Basic f32 tiled GEMM: C[M,N] = A[M,K] * B[K,N] (+ Cin). 64x64 tile, BK=16,
// 256 threads, 4x4 micro-tile per thread.
__global__ __launch_bounds__(256) void k_gemm(const float* __restrict__ A,
                                              const float* __restrict__ B,
                                              const float* __restrict__ Cin,
                                              float* __restrict__ Cout,
                                              int M, int N, int K) {
    __shared__ float As[16][65];  // [k][m] (transposed on store)
    __shared__ float Bs[16][65];  // [k][n]
    const int tid = threadIdx.x;
    const int m0 = blockIdx.y * 64;
    const int n0 = blockIdx.x * 64;
    const int ty = tid >> 4;        // 0..15
    const int tx = tid & 15;        // 0..15
    const int ar = tid >> 2;        // 0..63 (A row in tile)
    const int ak = (tid & 3) * 4;   // 0,4,8,12
    const int bk = tid >> 4;        // 0..15 (B k-row in tile)
    const int bc = (tid & 15) * 4;  // 0..60

    float acc[4][4] = {};

    for (int k0 = 0; k0 < K; k0 += 16) {
        // stage A tile (64x16), transposed into As[k][m]
        float4 a4 = make_float4(0.f, 0.f, 0.f, 0.f);
        int arow = m0 + ar;
        if (arow < M)
            a4 = *reinterpret_cast<const float4*>(A + (size_t)arow * K + k0 + ak);
        As[ak + 0][ar] = a4.x;
        As[ak + 1][ar] = a4.y;
        As[ak + 2][ar] = a4.z;
        As[ak + 3][ar] = a4.w;
        // stage B tile (16x64)
        int bcol = n0 + bc;
        float4 b4 = make_float4(0.f, 0.f, 0.f, 0.f);
        if (bcol + 3 < N) {
            b4 = *reinterpret_cast<const float4*>(B + (size_t)(k0 + bk) * N + bcol);
        } else {
            float tmp[4] = {0.f, 0.f, 0.f, 0.f};
            for (int j = 0; j < 4; ++j)
                if (bcol + j < N) tmp[j] = B[(size_t)(k0 + bk) * N + bcol + j];
            b4 = make_float4(tmp[0], tmp[1], tmp[2], tmp[3]);
        }
        Bs[bk][bc + 0] = b4.x;
        Bs[bk][bc + 1] = b4.y;
        Bs[bk][bc + 2] = b4.z;
        Bs[bk][bc + 3] = b4.w;
        __syncthreads();
#pragma unroll
        for (int kk = 0; kk < 16; ++kk) {
            float a_[4], b_[4];
#pragma unroll
            for (int i = 0; i < 4; ++i) a_[i] = As[kk][ty * 4 + i];
#pragma unroll
            for (int j = 0; j < 4; ++j) b_[j] = Bs[kk][tx * 4 + j];
#pragma unroll
            for (int i = 0; i < 4; ++i)
#pragma unroll
                for (int j = 0; j < 4; ++j) acc[i][j] += a_[i] * b_[j];
        }
        __syncthreads();
    }

    for (int i = 0; i < 4; ++i) {
        int row = m0 + ty * 4 + i;
        if (row >= M) continue;
        for (int j = 0; j < 4; ++j) {
            int col = n0 + tx * 4 + j;
            if (col >= N) continue;
            float vv = acc[i][j];
            if (Cin) vv += Cin[(size_t)row * N + col];
            Cout[(size_t)row * N + col] = vv;
        }
    }
}

}  // namespace

extern "C" void kernel_launch(void* const* d_in, const int* in_sizes, int n_in,
                              void* d_out, int out_size, void* d_ws, size_t ws_size,
                              hipStream_t stream) {
    const float* hs     = (const float*)d_in[0];
    const int*   coords = (const int*)d_in[1];
    const float* w_down = (const float*)d_in[2];
    const float* w3     = (const float*)d_in[3];
    const float* w2     = (const float*)d_in[4];
    const float* w_up   = (const float*)d_in[5];
    float* out = (float*)d_out;

    float* ws    = (float*)d_ws;
    float* xbuf  = ws;                              // NPTS*CD (x, later reused as pt_feat)
    float* smbuf = xbuf + (size_t)NPTS * CD;        // NPTS*CD
    float* cnt   = smbuf + (size_t)NPTS * CD;       // NVOX
    float* sums  = cnt + NVOX;                      // NVOX*CD

    // 1. zero count grid + touched sum cells
    k_zero_cnt<<<dim3((NVOX + 255) / 256), dim3(256), 0, stream>>>(cnt);
    k_zero_touched<<<dim3(NPTS), dim3(CD), 0, stream>>>(coords, sums);

    // 2. x = hs @ w_down   (5832x1152 * 1152x288)
    k_gemm<<<dim3((CD + 63) / 64, (NPTS + 63) / 64), dim3(256), 0, stream>>>(
        hs, w_down, nullptr, xbuf, NPTS, CD, C);

    // 3. scatter-mean accumulation
    k_scatter<<<dim3(NPTS), dim3(CD), 0, stream>>>(coords, xbuf, sums, cnt);

    // 4. depthwise conv3d + gelu, evaluated only at gathered voxels
    k_conv3_gather<<<dim3(NPTS), dim3(CD), 0, stream>>>(coords, sums, cnt, w3, xbuf);

    // 5. depthwise conv2d over (V,27,27,CD)
    k_conv2<<<dim3(NPTS), dim3(CD), 0, stream>>>(xbuf, w2, smbuf);

    // 6. out = hs + sm @ w_up   (5832x288 * 288x1152)
    k_gemm<<<dim3((C + 63) / 64, (NPTS + 63) / 64), dim3(256), 0, stream>>>(
        smbuf, w_up, hs, out, NPTS, C, CD);
}

// Round 2
// 154.394 us; speedup vs baseline: 1.7553x; 1.7553x over previous
//
#include <hip/hip_runtime.h>

namespace {

constexpr int GV   = 48;
constexpr int NV   = 8;
constexpr int NH   = 27;
constexpr int NW   = 27;
constexpr int L    = NH * NW;     // 729
constexpr int C    = 1152;
constexpr int CD   = 288;
constexpr int NPTS = NV * L;      // 5832
constexpr int NVOX = GV * GV * GV;// 110592

typedef __attribute__((ext_vector_type(8))) short short8;
typedef __attribute__((ext_vector_type(4))) float f32x4;

__global__ __launch_bounds__(256) void k_zero_cnt(float* __restrict__ cnt) {
    int i = blockIdx.x * 256 + threadIdx.x;
    if (i < NVOX) cnt[i] = 0.f;
}

// Zero only the voxel cells that will be scattered into (sums grid is otherwise
// never read: conv gather guards on cnt>0).
__global__ __launch_bounds__(CD) void k_zero_touched(const int* __restrict__ coords,
                                                     float* __restrict__ sums) {
    int p = blockIdx.x;
    int c0 = coords[p * 3 + 0], c1 = coords[p * 3 + 1], c2 = coords[p * 3 + 2];
    int flat = (c0 * GV + c1) * GV + c2;
    sums[(size_t)flat * CD + threadIdx.x] = 0.f;
}

__global__ __launch_bounds__(CD) void k_scatter(const int* __restrict__ coords,
                                                const float* __restrict__ x,
                                                float* __restrict__ sums,
                                                float* __restrict__ cnt) {
    int p = blockIdx.x;
    int t = threadIdx.x;
    int c0 = coords[p * 3 + 0], c1 = coords[p * 3 + 1], c2 = coords[p * 3 + 2];
    int flat = (c0 * GV + c1) * GV + c2;
    atomicAdd(&sums[(size_t)flat * CD + t], x[(size_t)p * CD + t]);
    if (t == 0) atomicAdd(&cnt[flat], 1.0f);
}

__device__ __forceinline__ float gelu_tanh(float a) {
    float a3 = a * a * a;
    float inner = 0.7978845608028654f * (a + 0.044715f * a3);
    return 0.5f * a * (1.0f + tanhf(inner));
}

// Depthwise 3x3x3 conv evaluated ONLY at gathered voxels, + gelu.
__global__ __launch_bounds__(CD) void k_conv3_gather(const int* __restrict__ coords,
                                                     const float* __restrict__ sums,
                                                     const float* __restrict__ cnt,
                                                     const float* __restrict__ w3,
                                                     float* __restrict__ ptf) {
    int p = blockIdx.x;
    int t = threadIdx.x;
    int c0 = coords[p * 3 + 0], c1 = coords[p * 3 + 1], c2 = coords[p * 3 + 2];
    float acc = 0.f;
#pragma unroll
    for (int dz = 0; dz < 3; ++dz) {
        int z = c0 + dz - 1;
        if ((unsigned)z >= (unsigned)GV) continue;
#pragma unroll
        for (int dy = 0; dy < 3; ++dy) {
            int y = c1 + dy - 1;
            if ((unsigned)y >= (unsigned)GV) continue;
#pragma unroll
            for (int dx = 0; dx < 3; ++dx) {
                int x2 = c2 + dx - 1;
                if ((unsigned)x2 >= (unsigned)GV) continue;
                int n = (z * GV + y) * GV + x2;
                float cv = cnt[n];             // broadcast across block
                if (cv > 0.f) {
                    float w = w3[t * 27 + dz * 9 + dy * 3 + dx];
                    acc += w * (sums[(size_t)n * CD + t] / cv);
                }
            }
        }
    }
    ptf[(size_t)p * CD + t] = gelu_tanh(acc);
}

// Depthwise 3x3 conv2d over (V,27,27,CD) channel-last.
__global__ __launch_bounds__(CD) void k_conv2(const float* __restrict__ ptf,
                                              const float* __restrict__ w2,
                                              float* __restrict__ sm) {
    int p = blockIdx.x;
    int t = threadIdx.x;
    int v = p / L;
    int rem = p - v * L;
    int y = rem / NW;
    int x = rem - y * NW;
    float acc = 0.f;
#pragma unroll
    for (int dy = 0; dy < 3; ++dy) {
        int yy = y + dy - 1;
        if ((unsigned)yy >= (unsigned)NH) continue;
#pragma unroll
        for (int dx = 0; dx < 3; ++dx) {
            int xx = x + dx - 1;
            if ((unsigned)xx >= (unsigned)NW) continue;
            acc += w2[t * 9 + dy * 3 + dx] *
                   ptf[((size_t)v * L + yy * NW + xx) * CD + t];
        }
    }
    sm[(size_t)p * CD + t] = acc;
}

__device__ __forceinline__ unsigned short f2bf(float x) {
    unsigned u = __float_as_uint(x);
    unsigned r = u + 0x7fffu + ((u >> 16) & 1u);   // round-to-nearest-even
    return (unsigned short)(r >> 16);
}

// Swizzled LDS element offset for a [rows][32] bf16 tile. col8 = 16B slot (0..3).
// XOR slot with ((row>>1)&3): spreads 16 same-slot rows across banks; residual
// 2-way conflicts are free on CDNA4.
__device__ __forceinline__ int swz(int row, int col8) {
    return row * 32 + ((col8 ^ ((row >> 1) & 3)) << 3);
}

// bf16 MFMA GEMM: Cout[M,N] = A[M,K]*B[K,N] (+Cin). f32 inputs, converted to
// bf16 during LDS staging. BM=64, BN=96, BK=32; 256 threads = 4 waves (2x2),
// per-wave output 32x48 = 2x3 fragments of 16x16.
__global__ __launch_bounds__(256) void k_gemm_mfma(const float* __restrict__ A,
                                                   const float* __restrict__ B,
                                                   const float* __restrict__ Cin,
                                                   float* __restrict__ Cout,
                                                   int M, int N, int K) {
    __shared__ unsigned short As[64 * 32];   // [row][k] swizzled, 4 KB
    __shared__ unsigned short Bs[96 * 32];   // [n][k] (B transposed) swizzled, 6 KB

    const int tid  = threadIdx.x;
    const int lane = tid & 63;
    const int wave = tid >> 6;          // 0..3
    const int wm   = wave >> 1;         // 0..1
    const int wn   = wave & 1;          // 0..1
    const int m0   = blockIdx.y * 64;
    const int n0   = blockIdx.x * 96;

    // A staging coords: 64 rows x 32 k, 8 f32 per thread
    const int ar = tid >> 2;            // 0..63
    const int ak = (tid & 3) * 8;       // 0,8,16,24

    f32x4 acc[2][3];
#pragma unroll
    for (int m = 0; m < 2; ++m)
#pragma unroll
        for (int n = 0; n < 3; ++n) acc[m][n] = (f32x4){0.f, 0.f, 0.f, 0.f};

    const int nsteps = K / 32;
    for (int kt = 0; kt < nsteps; ++kt) {
        const int kb = kt * 32;
        // ---- stage A (64x32 f32 -> bf16, swizzled) ----
        {
            float4 f0 = make_float4(0.f, 0.f, 0.f, 0.f);
            float4 f1 = make_float4(0.f, 0.f, 0.f, 0.f);
            int grow = m0 + ar;
            if (grow < M) {
                const float* p = A + (size_t)grow * K + kb + ak;
                f0 = *reinterpret_cast<const float4*>(p);
                f1 = *reinterpret_cast<const float4*>(p + 4);
            }
            short8 h;
            h[0] = (short)f2bf(f0.x); h[1] = (short)f2bf(f0.y);
            h[2] = (short)f2bf(f0.z); h[3] = (short)f2bf(f0.w);
            h[4] = (short)f2bf(f1.x); h[5] = (short)f2bf(f1.y);
            h[6] = (short)f2bf(f1.z); h[7] = (short)f2bf(f1.w);
            *reinterpret_cast<short8*>(&As[swz(ar, ak >> 3)]) = h;
        }
        // ---- stage B transposed (32x96 f32 -> Bs[n][k] bf16, swizzled) ----
        {
#pragma unroll
            for (int i = 0; i < 3; ++i) {
                int task = tid + i * 256;       // 0..767
                int n = task % 96;
                int g = task / 96;              // 0..7 (k quad)
                const float* p = B + (size_t)(kb + g * 4) * N + n0 + n;
                ushort4 hh;
                hh.x = f2bf(p[0 * N]);
                hh.y = f2bf(p[1 * N]);
                hh.z = f2bf(p[2 * N]);
                hh.w = f2bf(p[3 * N]);
                int off = n * 32 + (((g >> 1) ^ ((n >> 1) & 3)) << 3) + (g & 1) * 4;
                *reinterpret_cast<ushort4*>(&Bs[off]) = hh;
            }
        }
        __syncthreads();
        // ---- fragments + MFMA ----
        {
            short8 afrag[2], bfrag[3];
            const int kgrp = lane >> 4;     // 0..3 (16B slot)
            const int lr   = lane & 15;
#pragma unroll
            for (int m = 0; m < 2; ++m) {
                int r = wm * 32 + m * 16 + lr;
                afrag[m] = *reinterpret_cast<const short8*>(&As[swz(r, kgrp)]);
            }
#pragma unroll
            for (int n = 0; n < 3; ++n) {
                int c = wn * 48 + n * 16 + lr;
                bfrag[n] = *reinterpret_cast<const short8*>(&Bs[swz(c, kgrp)]);
            }
#pragma unroll
            for (int m = 0; m < 2; ++m)
#pragma unroll
                for (int n = 0; n < 3; ++n)
                    acc[m][n] = __builtin_amdgcn_mfma_f32_16x16x32_bf16(
                        afrag[m], bfrag[n], acc[m][n], 0, 0, 0);
        }
        __syncthreads();
    }

    // ---- epilogue: C write (+ optional residual) ----
    const int lr = lane & 15;
    const int rq = lane >> 4;           // row quad
#pragma unroll
    for (int m = 0; m < 2; ++m) {
        int rbase = m0 + wm * 32 + m * 16 + rq * 4;
#pragma unroll
        for (int n = 0; n < 3; ++n) {
            int col = n0 + wn * 48 + n * 16 + lr;
#pragma unroll
            for (int r = 0; r < 4; ++r) {
                int row = rbase + r;
                if (row < M) {
                    float v = acc[m][n][r];
                    if (Cin) v += Cin[(size_t)row * N + col];
                    Cout[(size_t)row * N + col] = v;
                }
            }
        }
    }
}

}  // namespace

extern "C" void kernel_launch(void* const* d_in, const int* in_sizes, int n_in,
                              void* d_out, int out_size, void* d_ws, size_t ws_size,
                              hipStream_t stream) {
    const float* hs     = (const float*)d_in[0];
    const int*   coords = (const int*)d_in[1];
    const float* w_down = (const float*)d_in[2];
    const float* w3     = (const float*)d_in[3];
    const float* w2     = (const float*)d_in[4];
    const float* w_up   = (const float*)d_in[5];
    float* out = (float*)d_out;

    float* ws    = (float*)d_ws;
    float* xbuf  = ws;                              // NPTS*CD (x, later reused as pt_feat)
    float* smbuf = xbuf + (size_t)NPTS * CD;        // NPTS*CD
    float* cnt   = smbuf + (size_t)NPTS * CD;       // NVOX
    float* sums  = cnt + NVOX;                      // NVOX*CD

    // 1. zero count grid + touched sum cells
    k_zero_cnt<<<dim3((NVOX + 255) / 256), dim3(256), 0, stream>>>(cnt);
    k_zero_touched<<<dim3(NPTS), dim3(CD), 0, stream>>>(coords, sums);

    // 2. x = hs @ w_down   (5832x1152 * 1152x288)
    k_gemm_mfma<<<dim3(CD / 96, (NPTS + 63) / 64), dim3(256), 0, stream>>>(
        hs, w_down, nullptr, xbuf, NPTS, CD, C);

    // 3. scatter-mean accumulation
    k_scatter<<<dim3(NPTS), dim3(CD), 0, stream>>>(coords, xbuf, sums, cnt);

    // 4. depthwise conv3d + gelu, evaluated only at gathered voxels
    k_conv3_gather<<<dim3(NPTS), dim3(CD), 0, stream>>>(coords, sums, cnt, w3, xbuf);

    // 5. depthwise conv2d over (V,27,27,CD)
    k_conv2<<<dim3(NPTS), dim3(CD), 0, stream>>>(xbuf, w2, smbuf);

    // 6. out = hs + sm @ w_up   (5832x288 * 288x1152)
    k_gemm_mfma<<<dim3(C / 96, (NPTS + 63) / 64), dim3(256), 0, stream>>>(
        smbuf, w_up, hs, out, NPTS, C, CD);
}

// Round 3
// 121.113 us; speedup vs baseline: 2.2376x; 1.2748x over previous
//
#include <hip/hip_runtime.h>

namespace {

constexpr int GV   = 48;
constexpr int NV   = 8;
constexpr int NH   = 27;
constexpr int NW   = 27;
constexpr int L    = NH * NW;     // 729
constexpr int C    = 1152;
constexpr int CD   = 288;
constexpr int NPTS = NV * L;      // 5832
constexpr int NVOX = GV * GV * GV;// 110592

typedef __attribute__((ext_vector_type(8))) short short8;
typedef __attribute__((ext_vector_type(4))) float f32x4;

__global__ __launch_bounds__(256) void k_zero_cnt(float* __restrict__ cnt) {
    int i = blockIdx.x * 256 + threadIdx.x;
    if (i < NVOX) cnt[i] = 0.f;
}

// Zero only the voxel cells that will be scattered into (sums grid is otherwise
// never read: conv gather guards on cnt>0).
__global__ __launch_bounds__(CD) void k_zero_touched(const int* __restrict__ coords,
                                                     float* __restrict__ sums) {
    int p = blockIdx.x;
    int c0 = coords[p * 3 + 0], c1 = coords[p * 3 + 1], c2 = coords[p * 3 + 2];
    int flat = (c0 * GV + c1) * GV + c2;
    sums[(size_t)flat * CD + threadIdx.x] = 0.f;
}

__global__ __launch_bounds__(CD) void k_scatter(const int* __restrict__ coords,
                                                const float* __restrict__ x,
                                                float* __restrict__ sums,
                                                float* __restrict__ cnt) {
    int p = blockIdx.x;
    int t = threadIdx.x;
    int c0 = coords[p * 3 + 0], c1 = coords[p * 3 + 1], c2 = coords[p * 3 + 2];
    int flat = (c0 * GV + c1) * GV + c2;
    atomicAdd(&sums[(size_t)flat * CD + t], x[(size_t)p * CD + t]);
    if (t == 0) atomicAdd(&cnt[flat], 1.0f);
}

__device__ __forceinline__ float gelu_tanh(float a) {
    float a3 = a * a * a;
    float inner = 0.7978845608028654f * (a + 0.044715f * a3);
    return 0.5f * a * (1.0f + tanhf(inner));
}

// Depthwise 3x3x3 conv evaluated ONLY at gathered voxels, + gelu.
__global__ __launch_bounds__(CD) void k_conv3_gather(const int* __restrict__ coords,
                                                     const float* __restrict__ sums,
                                                     const float* __restrict__ cnt,
                                                     const float* __restrict__ w3,
                                                     float* __restrict__ ptf) {
    int p = blockIdx.x;
    int t = threadIdx.x;
    int c0 = coords[p * 3 + 0], c1 = coords[p * 3 + 1], c2 = coords[p * 3 + 2];
    float acc = 0.f;
#pragma unroll
    for (int dz = 0; dz < 3; ++dz) {
        int z = c0 + dz - 1;
        if ((unsigned)z >= (unsigned)GV) continue;
#pragma unroll
        for (int dy = 0; dy < 3; ++dy) {
            int y = c1 + dy - 1;
            if ((unsigned)y >= (unsigned)GV) continue;
#pragma unroll
            for (int dx = 0; dx < 3; ++dx) {
                int x2 = c2 + dx - 1;
                if ((unsigned)x2 >= (unsigned)GV) continue;
                int n = (z * GV + y) * GV + x2;
                float cv = cnt[n];             // broadcast across block
                if (cv > 0.f) {
                    float w = w3[t * 27 + dz * 9 + dy * 3 + dx];
                    acc += w * (sums[(size_t)n * CD + t] / cv);
                }
            }
        }
    }
    ptf[(size_t)p * CD + t] = gelu_tanh(acc);
}

// Depthwise 3x3 conv2d over (V,27,27,CD) channel-last.
__global__ __launch_bounds__(CD) void k_conv2(const float* __restrict__ ptf,
                                              const float* __restrict__ w2,
                                              float* __restrict__ sm) {
    int p = blockIdx.x;
    int t = threadIdx.x;
    int v = p / L;
    int rem = p - v * L;
    int y = rem / NW;
    int x = rem - y * NW;
    float acc = 0.f;
#pragma unroll
    for (int dy = 0; dy < 3; ++dy) {
        int yy = y + dy - 1;
        if ((unsigned)yy >= (unsigned)NH) continue;
#pragma unroll
        for (int dx = 0; dx < 3; ++dx) {
            int xx = x + dx - 1;
            if ((unsigned)xx >= (unsigned)NW) continue;
            acc += w2[t * 9 + dy * 3 + dx] *
                   ptf[((size_t)v * L + yy * NW + xx) * CD + t];
        }
    }
    sm[(size_t)p * CD + t] = acc;
}

__device__ __forceinline__ unsigned short f2bf(float x) {
    unsigned u = __float_as_uint(x);
    unsigned r = u + 0x7fffu + ((u >> 16) & 1u);   // round-to-nearest-even
    return (unsigned short)(r >> 16);
}

// Swizzled LDS element offset for a [rows][32] bf16 tile. slot = 16B unit (0..3).
// XOR slot with ((row>>1)&3): residual 2-way conflicts are free on CDNA4.
__device__ __forceinline__ int swz(int row, int slot) {
    return row * 32 + ((slot ^ ((row >> 1) & 3)) << 3);
}

// bf16 MFMA GEMM, software-pipelined: double-buffered LDS, register-staged
// prefetch issued one iteration ahead, ONE barrier per K-step.
// Cout[M,N] = A[M,K]*B[K,N] (+Cin). BN=96 fixed, BK=32, 256 threads = 4 waves
// (2x2); per-wave output (BM/2)x48. BM=32 (MR=1) or BM=64 (MR=2).
template<int BM>
__global__ __launch_bounds__(256) void k_gemm_mfma(const float* __restrict__ A,
                                                   const float* __restrict__ B,
                                                   const float* __restrict__ Cin,
                                                   float* __restrict__ Cout,
                                                   int M, int N, int K) {
    constexpr int MR = BM / 32;               // 16x16 row-frags per wave
    __shared__ unsigned short As[2][BM * 32];
    __shared__ unsigned short Bs[2][96 * 32];

    const int tid  = threadIdx.x;
    const int lane = tid & 63;
    const int wave = tid >> 6;          // 0..3
    const int wm   = wave >> 1;         // 0..1
    const int wn   = wave & 1;          // 0..1
    const int m0   = blockIdx.y * BM;
    const int n0   = blockIdx.x * 96;

    // A staging coords
    int ar, ak;
    if constexpr (BM == 64) { ar = tid >> 2; ak = (tid & 3) * 8; }
    else                    { ar = tid >> 3; ak = (tid & 7) * 4; }
    const bool avalid = (m0 + ar) < M;
    const float* Aptr = A + (size_t)(m0 + ar) * K + ak;

    // B staging coords: 3 tasks/thread, each 4 k-consecutive elems of column n
    int bn[3], bkq[3];
#pragma unroll
    for (int i = 0; i < 3; ++i) {
        int task = tid + i * 256;
        bn[i]  = task % 96;
        bkq[i] = task / 96;             // 0..7
    }

    float4 areg[MR];
    float  breg[3][4];

    auto LOAD = [&](int kt) {
        const int kb = kt * 32;
        if (avalid) {
            areg[0] = *reinterpret_cast<const float4*>(Aptr + kb);
            if constexpr (BM == 64)
                areg[1] = *reinterpret_cast<const float4*>(Aptr + kb + 4);
        } else {
            areg[0] = make_float4(0.f, 0.f, 0.f, 0.f);
            if constexpr (BM == 64) areg[1] = make_float4(0.f, 0.f, 0.f, 0.f);
        }
#pragma unroll
        for (int i = 0; i < 3; ++i) {
            const float* p = B + (size_t)(kb + bkq[i] * 4) * N + n0 + bn[i];
#pragma unroll
            for (int j = 0; j < 4; ++j) breg[i][j] = p[(size_t)j * N];
        }
    };

    auto STAGE = [&](int buf) {
        if constexpr (BM == 64) {
            short8 h;
            h[0] = (short)f2bf(areg[0].x); h[1] = (short)f2bf(areg[0].y);
            h[2] = (short)f2bf(areg[0].z); h[3] = (short)f2bf(areg[0].w);
            h[4] = (short)f2bf(areg[1].x); h[5] = (short)f2bf(areg[1].y);
            h[6] = (short)f2bf(areg[1].z); h[7] = (short)f2bf(areg[1].w);
            *reinterpret_cast<short8*>(&As[buf][swz(ar, ak >> 3)]) = h;
        } else {
            ushort4 h;
            h.x = f2bf(areg[0].x); h.y = f2bf(areg[0].y);
            h.z = f2bf(areg[0].z); h.w = f2bf(areg[0].w);
            int off = ar * 32 + (((ak >> 3) ^ ((ar >> 1) & 3)) << 3) + (ak & 7);
            *reinterpret_cast<ushort4*>(&As[buf][off]) = h;
        }
#pragma unroll
        for (int i = 0; i < 3; ++i) {
            ushort4 hh;
            hh.x = f2bf(breg[i][0]); hh.y = f2bf(breg[i][1]);
            hh.z = f2bf(breg[i][2]); hh.w = f2bf(breg[i][3]);
            int off = bn[i] * 32 + (((bkq[i] >> 1) ^ ((bn[i] >> 1) & 3)) << 3) +
                      (bkq[i] & 1) * 4;
            *reinterpret_cast<ushort4*>(&Bs[buf][off]) = hh;
        }
    };

    f32x4 acc[MR][3];
#pragma unroll
    for (int m = 0; m < MR; ++m)
#pragma unroll
        for (int n = 0; n < 3; ++n) acc[m][n] = (f32x4){0.f, 0.f, 0.f, 0.f};

    const int nsteps = K / 32;

    // prologue: tile 0 -> LDS buf0; tile 1 loads in flight
    LOAD(0);
    STAGE(0);
    if (nsteps > 1) LOAD(1);
    __syncthreads();

    const int kgrp = lane >> 4;     // 16B slot
    const int lr   = lane & 15;

    for (int kt = 0; kt < nsteps; ++kt) {
        const int cur = kt & 1;
        short8 afrag[MR], bfrag[3];
#pragma unroll
        for (int m = 0; m < MR; ++m) {
            int r = wm * (BM / 2) + m * 16 + lr;
            afrag[m] = *reinterpret_cast<const short8*>(&As[cur][swz(r, kgrp)]);
        }
#pragma unroll
        for (int n = 0; n < 3; ++n) {
            int c = wn * 48 + n * 16 + lr;
            bfrag[n] = *reinterpret_cast<const short8*>(&Bs[cur][swz(c, kgrp)]);
        }
        // stage tile kt+1 (regs -> other LDS buffer), then issue loads for kt+2
        if (kt + 1 < nsteps) {
            STAGE(cur ^ 1);
            if (kt + 2 < nsteps) LOAD(kt + 2);
        }
#pragma unroll
        for (int m = 0; m < MR; ++m)
#pragma unroll
            for (int n = 0; n < 3; ++n)
                acc[m][n] = __builtin_amdgcn_mfma_f32_16x16x32_bf16(
                    afrag[m], bfrag[n], acc[m][n], 0, 0, 0);
        if (kt + 1 < nsteps) __syncthreads();
    }

    // ---- epilogue: C write (+ optional residual) ----
    const int rq = lane >> 4;           // row quad
#pragma unroll
    for (int m = 0; m < MR; ++m) {
        int rbase = m0 + wm * (BM / 2) + m * 16 + rq * 4;
#pragma unroll
        for (int n = 0; n < 3; ++n) {
            int col = n0 + wn * 48 + n * 16 + lr;
#pragma unroll
            for (int r = 0; r < 4; ++r) {
                int row = rbase + r;
                if (row < M) {
                    float v = acc[m][n][r];
                    if (Cin) v += Cin[(size_t)row * N + col];
                    Cout[(size_t)row * N + col] = v;
                }
            }
        }
    }
}

}  // namespace

extern "C" void kernel_launch(void* const* d_in, const int* in_sizes, int n_in,
                              void* d_out, int out_size, void* d_ws, size_t ws_size,
                              hipStream_t stream) {
    const float* hs     = (const float*)d_in[0];
    const int*   coords = (const int*)d_in[1];
    const float* w_down = (const float*)d_in[2];
    const float* w3     = (const float*)d_in[3];
    const float* w2     = (const float*)d_in[4];
    const float* w_up   = (const float*)d_in[5];
    float* out = (float*)d_out;

    float* ws    = (float*)d_ws;
    float* xbuf  = ws;                              // NPTS*CD (x, later reused as pt_feat)
    float* smbuf = xbuf + (size_t)NPTS * CD;        // NPTS*CD
    float* cnt   = smbuf + (size_t)NPTS * CD;       // NVOX
    float* sums  = cnt + NVOX;                      // NVOX*CD

    // 1. zero count grid + touched sum cells
    k_zero_cnt<<<dim3((NVOX + 255) / 256), dim3(256), 0, stream>>>(cnt);
    k_zero_touched<<<dim3(NPTS), dim3(CD), 0, stream>>>(coords, sums);

    // 2. x = hs @ w_down   (5832x1152 * 1152x288)  BM=32 -> 3x183 = 549 blocks
    k_gemm_mfma<32><<<dim3(CD / 96, (NPTS + 31) / 32), dim3(256), 0, stream>>>(
        hs, w_down, nullptr, xbuf, NPTS, CD, C);

    // 3. scatter-mean accumulation
    k_scatter<<<dim3(NPTS), dim3(CD), 0, stream>>>(coords, xbuf, sums, cnt);

    // 4. depthwise conv3d + gelu, evaluated only at gathered voxels
    k_conv3_gather<<<dim3(NPTS), dim3(CD), 0, stream>>>(coords, sums, cnt, w3, xbuf);

    // 5. depthwise conv2d over (V,27,27,CD)
    k_conv2<<<dim3(NPTS), dim3(CD), 0, stream>>>(xbuf, w2, smbuf);

    // 6. out = hs + sm @ w_up   (5832x288 * 288x1152)  BM=64 -> 12x92 = 1104 blocks
    k_gemm_mfma<64><<<dim3(C / 96, (NPTS + 63) / 64), dim3(256), 0, stream>>>(
        smbuf, w_up, hs, out, NPTS, C, CD);
}

// Round 4
// 112.132 us; speedup vs baseline: 2.4169x; 1.0801x over previous
//
#include <hip/hip_runtime.h>

namespace {

constexpr int GV   = 48;
constexpr int NV   = 8;
constexpr int NH   = 27;
constexpr int NW   = 27;
constexpr int L    = NH * NW;     // 729
constexpr int C    = 1152;
constexpr int CD   = 288;
constexpr int NPTS = NV * L;      // 5832
constexpr int NVOX = GV * GV * GV;// 110592

typedef __attribute__((ext_vector_type(8))) short short8;
typedef __attribute__((ext_vector_type(4))) float f32x4;

__device__ __forceinline__ unsigned short f2bf(float x) {
    unsigned u = __float_as_uint(x);
    unsigned r = u + 0x7fffu + ((u >> 16) & 1u);   // round-to-nearest-even
    return (unsigned short)(r >> 16);
}

__global__ __launch_bounds__(256) void k_zero_cnt(float* __restrict__ cnt) {
    int i = blockIdx.x * 256 + threadIdx.x;
    if (i < NVOX) cnt[i] = 0.f;
}

// Zero only the voxel cells that will be scattered into.
__global__ __launch_bounds__(CD) void k_zero_touched(const int* __restrict__ coords,
                                                     float* __restrict__ sums) {
    int p = blockIdx.x;
    int c0 = coords[p * 3 + 0], c1 = coords[p * 3 + 1], c2 = coords[p * 3 + 2];
    int flat = (c0 * GV + c1) * GV + c2;
    sums[(size_t)flat * CD + threadIdx.x] = 0.f;
}

// f32 -> bf16 bulk convert, 8 elems/thread.
__global__ __launch_bounds__(256) void k_cvt_bf16(const float* __restrict__ in,
                                                  unsigned short* __restrict__ out,
                                                  int n8) {
    int i = blockIdx.x * 256 + threadIdx.x;
    if (i >= n8) return;
    const float4* p = reinterpret_cast<const float4*>(in + (size_t)i * 8);
    float4 a = p[0], b = p[1];
    short8 h;
    h[0] = (short)f2bf(a.x); h[1] = (short)f2bf(a.y);
    h[2] = (short)f2bf(a.z); h[3] = (short)f2bf(a.w);
    h[4] = (short)f2bf(b.x); h[5] = (short)f2bf(b.y);
    h[6] = (short)f2bf(b.z); h[7] = (short)f2bf(b.w);
    *reinterpret_cast<short8*>(out + (size_t)i * 8) = h;
}

// Wt[n][k] = bf16(W[k][n]).  W: K x N f32, K%32==0, N%32==0.
__global__ __launch_bounds__(256) void k_transpose_cvt(const float* __restrict__ W,
                                                       unsigned short* __restrict__ Wt,
                                                       int K, int N) {
    __shared__ float t[32][33];
    const int tid = threadIdx.x;
    const int kb = blockIdx.x * 32, nb = blockIdx.y * 32;
#pragma unroll
    for (int i = 0; i < 4; ++i) {
        int r = (tid >> 5) + i * 8;     // k
        int c = tid & 31;               // n
        t[r][c] = W[(size_t)(kb + r) * N + nb + c];
    }
    __syncthreads();
#pragma unroll
    for (int i = 0; i < 4; ++i) {
        int r = (tid >> 5) + i * 8;     // n
        int c = tid & 31;               // k
        Wt[(size_t)(nb + r) * K + kb + c] = f2bf(t[c][r]);
    }
}

__global__ __launch_bounds__(CD) void k_scatter(const int* __restrict__ coords,
                                                const float* __restrict__ x,
                                                float* __restrict__ sums,
                                                float* __restrict__ cnt) {
    int p = blockIdx.x;
    int t = threadIdx.x;
    int c0 = coords[p * 3 + 0], c1 = coords[p * 3 + 1], c2 = coords[p * 3 + 2];
    int flat = (c0 * GV + c1) * GV + c2;
    atomicAdd(&sums[(size_t)flat * CD + t], x[(size_t)p * CD + t]);
    if (t == 0) atomicAdd(&cnt[flat], 1.0f);
}

__device__ __forceinline__ float gelu_tanh(float a) {
    float a3 = a * a * a;
    float inner = 0.7978845608028654f * (a + 0.044715f * a3);
    return 0.5f * a * (1.0f + tanhf(inner));
}

// Depthwise 3x3x3 conv evaluated ONLY at gathered voxels, + gelu.
__global__ __launch_bounds__(CD) void k_conv3_gather(const int* __restrict__ coords,
                                                     const float* __restrict__ sums,
                                                     const float* __restrict__ cnt,
                                                     const float* __restrict__ w3,
                                                     float* __restrict__ ptf) {
    int p = blockIdx.x;
    int t = threadIdx.x;
    int c0 = coords[p * 3 + 0], c1 = coords[p * 3 + 1], c2 = coords[p * 3 + 2];
    float acc = 0.f;
#pragma unroll
    for (int dz = 0; dz < 3; ++dz) {
        int z = c0 + dz - 1;
        if ((unsigned)z >= (unsigned)GV) continue;
#pragma unroll
        for (int dy = 0; dy < 3; ++dy) {
            int y = c1 + dy - 1;
            if ((unsigned)y >= (unsigned)GV) continue;
#pragma unroll
            for (int dx = 0; dx < 3; ++dx) {
                int x2 = c2 + dx - 1;
                if ((unsigned)x2 >= (unsigned)GV) continue;
                int n = (z * GV + y) * GV + x2;
                float cv = cnt[n];
                if (cv > 0.f) {
                    float w = w3[t * 27 + dz * 9 + dy * 3 + dx];
                    acc += w * (sums[(size_t)n * CD + t] / cv);
                }
            }
        }
    }
    ptf[(size_t)p * CD + t] = gelu_tanh(acc);
}

// Depthwise 3x3 conv2d over (V,27,27,CD); emits bf16 (GEMM2's A matrix).
__global__ __launch_bounds__(CD) void k_conv2(const float* __restrict__ ptf,
                                              const float* __restrict__ w2,
                                              unsigned short* __restrict__ sm) {
    int p = blockIdx.x;
    int t = threadIdx.x;
    int v = p / L;
    int rem = p - v * L;
    int y = rem / NW;
    int x = rem - y * NW;
    float acc = 0.f;
#pragma unroll
    for (int dy = 0; dy < 3; ++dy) {
        int yy = y + dy - 1;
        if ((unsigned)yy >= (unsigned)NH) continue;
#pragma unroll
        for (int dx = 0; dx < 3; ++dx) {
            int xx = x + dx - 1;
            if ((unsigned)xx >= (unsigned)NW) continue;
            acc += w2[t * 9 + dy * 3 + dx] *
                   ptf[((size_t)v * L + yy * NW + xx) * CD + t];
        }
    }
    sm[(size_t)p * CD + t] = f2bf(acc);
}

// Swizzled LDS element offset for a [rows][32] bf16 tile. slot = 16B unit (0..3).
__device__ __forceinline__ int swz(int row, int slot) {
    return row * 32 + ((slot ^ ((row >> 1) & 3)) << 3);
}

// bf16 MFMA GEMM, all-bf16 staging (pure 16B copies), double-buffered LDS,
// register prefetch one tile ahead, ONE barrier per K-step.
// Cout[M,N] = A[M,K] * Bt[N,K]^T (+Cin).  BN=96, BK=32, 256 thr = 4 waves (2x2).
template<int BM>
__global__ __launch_bounds__(256) void k_gemm_mfma(const unsigned short* __restrict__ A,
                                                   const unsigned short* __restrict__ Bt,
                                                   const float* __restrict__ Cin,
                                                   float* __restrict__ Cout,
                                                   int M, int N, int K) {
    constexpr int MR = BM / 32;
    __shared__ unsigned short As[2][BM * 32];
    __shared__ unsigned short Bs[2][96 * 32];

    const int tid  = threadIdx.x;
    const int lane = tid & 63;
    const int wave = tid >> 6;
    const int wm   = wave >> 1;
    const int wn   = wave & 1;
    const int m0   = blockIdx.y * BM;
    const int n0   = blockIdx.x * 96;

    // 16B-unit staging assignments.
    // B tile: 96 rows x 4 slots = 384 units: b0 = tid (all), b1 = 256+tid (tid<128).
    // A tile: BM*4 units: BM=64 -> all threads 1 unit; BM=32 -> threads 128..255.
    int a_unit;
    bool has_a;
    if constexpr (BM == 64) { a_unit = tid;       has_a = true; }
    else                    { a_unit = tid - 128; has_a = (tid >= 128); }
    const int a_row = a_unit >> 2, a_slot = a_unit & 3;
    const int b0_row = tid >> 2, b0_slot = tid & 3;
    const int b1_row = (tid + 256) >> 2, b1_slot = tid & 3;
    const bool has_b1 = (tid < 128);
    const bool avalid = has_a && (m0 + a_row) < M;

    short8 areg, breg0, breg1;

    auto LOAD = [&](int kt) {
        const int kb = kt * 32;
        if (avalid)
            areg = *reinterpret_cast<const short8*>(A + (size_t)(m0 + a_row) * K + kb + a_slot * 8);
        else
            areg = (short8){0, 0, 0, 0, 0, 0, 0, 0};
        breg0 = *reinterpret_cast<const short8*>(Bt + (size_t)(n0 + b0_row) * K + kb + b0_slot * 8);
        if (has_b1)
            breg1 = *reinterpret_cast<const short8*>(Bt + (size_t)(n0 + b1_row) * K + kb + b1_slot * 8);
    };

    auto STAGE = [&](int buf) {
        if (has_a)
            *reinterpret_cast<short8*>(&As[buf][swz(a_row, a_slot)]) = areg;
        *reinterpret_cast<short8*>(&Bs[buf][swz(b0_row, b0_slot)]) = breg0;
        if (has_b1)
            *reinterpret_cast<short8*>(&Bs[buf][swz(b1_row, b1_slot)]) = breg1;
    };

    f32x4 acc[MR][3];
#pragma unroll
    for (int m = 0; m < MR; ++m)
#pragma unroll
        for (int n = 0; n < 3; ++n) acc[m][n] = (f32x4){0.f, 0.f, 0.f, 0.f};

    const int nsteps = K / 32;

    LOAD(0);
    STAGE(0);
    if (nsteps > 1) LOAD(1);
    __syncthreads();

    const int kgrp = lane >> 4;
    const int lr   = lane & 15;

    for (int kt = 0; kt < nsteps; ++kt) {
        const int cur = kt & 1;
        short8 afrag[MR], bfrag[3];
#pragma unroll
        for (int m = 0; m < MR; ++m) {
            int r = wm * (BM / 2) + m * 16 + lr;
            afrag[m] = *reinterpret_cast<const short8*>(&As[cur][swz(r, kgrp)]);
        }
#pragma unroll
        for (int n = 0; n < 3; ++n) {
            int c = wn * 48 + n * 16 + lr;
            bfrag[n] = *reinterpret_cast<const short8*>(&Bs[cur][swz(c, kgrp)]);
        }
        if (kt + 1 < nsteps) {
            STAGE(cur ^ 1);
            if (kt + 2 < nsteps) LOAD(kt + 2);
        }
#pragma unroll
        for (int m = 0; m < MR; ++m)
#pragma unroll
            for (int n = 0; n < 3; ++n)
                acc[m][n] = __builtin_amdgcn_mfma_f32_16x16x32_bf16(
                    afrag[m], bfrag[n], acc[m][n], 0, 0, 0);
        if (kt + 1 < nsteps) __syncthreads();
    }

    const int rq = lane >> 4;
#pragma unroll
    for (int m = 0; m < MR; ++m) {
        int rbase = m0 + wm * (BM / 2) + m * 16 + rq * 4;
#pragma unroll
        for (int n = 0; n < 3; ++n) {
            int col = n0 + wn * 48 + n * 16 + lr;
#pragma unroll
            for (int r = 0; r < 4; ++r) {
                int row = rbase + r;
                if (row < M) {
                    float v = acc[m][n][r];
                    if (Cin) v += Cin[(size_t)row * N + col];
                    Cout[(size_t)row * N + col] = v;
                }
            }
        }
    }
}

}  // namespace

extern "C" void kernel_launch(void* const* d_in, const int* in_sizes, int n_in,
                              void* d_out, int out_size, void* d_ws, size_t ws_size,
                              hipStream_t stream) {
    const float* hs     = (const float*)d_in[0];
    const int*   coords = (const int*)d_in[1];
    const float* w_down = (const float*)d_in[2];
    const float* w3     = (const float*)d_in[3];
    const float* w2     = (const float*)d_in[4];
    const float* w_up   = (const float*)d_in[5];
    float* out = (float*)d_out;

    float* ws    = (float*)d_ws;
    float* xbuf  = ws;                                  // NPTS*CD f32
    float* cnt   = xbuf + (size_t)NPTS * CD;            // NVOX f32
    float* sums  = cnt + NVOX;                          // NVOX*CD f32
    unsigned short* hs_bf = (unsigned short*)(sums + (size_t)NVOX * CD); // NPTS*C
    unsigned short* smbuf = hs_bf + (size_t)NPTS * C;   // NPTS*CD bf16
    unsigned short* wdt   = smbuf + (size_t)NPTS * CD;  // [CD][C] bf16 (w_down^T)
    unsigned short* wut   = wdt + (size_t)CD * C;       // [C][CD] bf16 (w_up^T)

    // 0. precompute: bf16 conversions + weight transposes
    k_cvt_bf16<<<dim3((NPTS * C / 8 + 255) / 256), dim3(256), 0, stream>>>(
        hs, hs_bf, NPTS * C / 8);
    k_transpose_cvt<<<dim3(C / 32, CD / 32), dim3(256), 0, stream>>>(w_down, wdt, C, CD);
    k_transpose_cvt<<<dim3(CD / 32, C / 32), dim3(256), 0, stream>>>(w_up, wut, CD, C);

    // 1. zero count grid + touched sum cells
    k_zero_cnt<<<dim3((NVOX + 255) / 256), dim3(256), 0, stream>>>(cnt);
    k_zero_touched<<<dim3(NPTS), dim3(CD), 0, stream>>>(coords, sums);

    // 2. x = hs @ w_down   (5832x1152 * 1152x288)  BM=32 -> 3x183 = 549 blocks
    k_gemm_mfma<32><<<dim3(CD / 96, (NPTS + 31) / 32), dim3(256), 0, stream>>>(
        hs_bf, wdt, nullptr, xbuf, NPTS, CD, C);

    // 3. scatter-mean accumulation
    k_scatter<<<dim3(NPTS), dim3(CD), 0, stream>>>(coords, xbuf, sums, cnt);

    // 4. depthwise conv3d + gelu at gathered voxels
    k_conv3_gather<<<dim3(NPTS), dim3(CD), 0, stream>>>(coords, sums, cnt, w3, xbuf);

    // 5. depthwise conv2d, bf16 out
    k_conv2<<<dim3(NPTS), dim3(CD), 0, stream>>>(xbuf, w2, smbuf);

    // 6. out = hs + sm @ w_up   (5832x288 * 288x1152)  BM=64 -> 12x92 = 1104 blocks
    k_gemm_mfma<64><<<dim3(C / 96, (NPTS + 63) / 64), dim3(256), 0, stream>>>(
        smbuf, wut, hs, out, NPTS, C, CD);
}